// Round 8
// baseline (366.946 us; speedup 1.0000x reference)
//
#include <hip/hip_runtime.h>

#define LL 2048
#define NN 4
#define EE 768
#define HH 12
#define RR 16
#define HD 64
#define TT (LL*NN)    // 8192 tokens
#define F3 (3*EE)     // 2304
#define KA 832        // augmented K: 768 + 16 lora + 48 zero-pad (13 * 64)

typedef __bf16 bf16;
typedef bf16 bf16x4 __attribute__((ext_vector_type(4)));
typedef bf16 bf16x8 __attribute__((ext_vector_type(8)));
typedef float floatx4 __attribute__((ext_vector_type(4)));

// ---------------------------------------------------------------------------
// cast_x: streaming fp32 -> bf16 cast into Xa cols 0..767.
// ---------------------------------------------------------------------------
__global__ __launch_bounds__(256) void cast_x(
    const float* __restrict__ q, const float* __restrict__ k,
    const float* __restrict__ v, bf16* __restrict__ Xa)
{
    const int bid = blockIdx.x;           // 0..3071
    const int third = bid / (TT/8);       // 1024 blocks per third
    const int r0 = (bid % (TT/8)) * 8;
    const float* x = (third == 0) ? q : (third == 1) ? k : v;
    const int tid = threadIdx.x;
    #pragma unroll
    for (int i = 0; i < 6; ++i) {
        const int e4 = i*256 + tid;       // float4 index, 0..1535 (192 per row)
        const int row = e4 / 192;
        const int col = (e4 % 192) * 4;
        const float4 f = *(const float4*)(x + (size_t)(r0+row)*EE + col);
        bf16x4 h = { (bf16)f.x, (bf16)f.y, (bf16)f.z, (bf16)f.w };
        *(bf16x4*)(Xa + ((size_t)third*TT + r0 + row)*KA + col) = h;
    }
}

// ---------------------------------------------------------------------------
// prep_w: Wa bf16 [3072][KA]  +  Dm bf16 [4][16][768] (q/k/v/out down mats)
// ---------------------------------------------------------------------------
__global__ __launch_bounds__(256) void prep_w(
    const float* __restrict__ W,  const float* __restrict__ qu,
    const float* __restrict__ ku, const float* __restrict__ vu,
    const float* __restrict__ Wo, const float* __restrict__ ou,
    const float* __restrict__ qd, const float* __restrict__ kd,
    const float* __restrict__ vd, const float* __restrict__ odw,
    bf16* __restrict__ Wa, bf16* __restrict__ Dm)
{
    const int f = blockIdx.x;             // 0..3135
    const int tid = threadIdx.x;
    if (f < 3072) {
        const float* src;
        const float* up;
        if (f < F3) {
            const int third = f / EE, fe = f % EE;
            src = W + (size_t)f*EE;
            up  = ((third == 0) ? qu : (third == 1) ? ku : vu) + fe*RR;
        } else {
            const int fe = f - F3;
            src = Wo + (size_t)fe*EE;
            up  = ou + fe*RR;
        }
        bf16* row = Wa + (size_t)f*KA;
        #pragma unroll
        for (int i = 0; i < 3; ++i)
            row[i*256 + tid] = (bf16)src[i*256 + tid];
        if (tid < 64)
            row[EE + tid] = (tid < RR) ? (bf16)up[tid] : (bf16)0.f;
    } else {
        const int f2 = f - 3072;          // 0..63
        const int which = f2 >> 4, r = f2 & 15;
        const float* dsrc = (which == 0) ? qd : (which == 1) ? kd
                          : (which == 2) ? vd : odw;
        bf16* drow = Dm + (size_t)f2*EE;
        #pragma unroll
        for (int i = 0; i < 3; ++i)
            drow[i*256 + tid] = (bf16)dsrc[(size_t)r*EE + i*256 + tid];
    }
}

// ---------------------------------------------------------------------------
// lora_rank16: A[m][768+r] = sum_k A[m][k]*D[r][k]; cols 784..831 = 0.
// ---------------------------------------------------------------------------
template<int XA>
__global__ __launch_bounds__(256) void lora_rank16(
    bf16* __restrict__ A, const bf16* __restrict__ Dm)
{
    __shared__ float red[4][64][16];      // 16 KB
    const int row0 = blockIdx.x * 64;
    const int dn = XA ? (row0 >> 13) : 3; // row0 / TT
    const bf16* D = Dm + (size_t)dn*16*EE;
    const int tid = threadIdx.x;
    const int wave = tid >> 6, lane = tid & 63;
    const int quad = lane >> 4, l16 = lane & 15;

    floatx4 acc[4];
    #pragma unroll
    for (int rt = 0; rt < 4; ++rt) acc[rt] = (floatx4){0.f,0.f,0.f,0.f};

    #pragma unroll
    for (int ks = 0; ks < 6; ++ks) {
        const int k0 = wave*192 + ks*32;
        const bf16x8 b = *(const bf16x8*)(D + (size_t)l16*EE + k0 + quad*8);
        #pragma unroll
        for (int rt = 0; rt < 4; ++rt) {
            const bf16x8 a = *(const bf16x8*)(
                A + (size_t)(row0 + rt*16 + l16)*KA + k0 + quad*8);
            acc[rt] = __builtin_amdgcn_mfma_f32_16x16x32_bf16(a, b, acc[rt], 0, 0, 0);
        }
    }

    #pragma unroll
    for (int rt = 0; rt < 4; ++rt)
        #pragma unroll
        for (int rr = 0; rr < 4; ++rr)
            red[wave][rt*16 + quad*4 + rr][l16] = acc[rt][rr];
    __syncthreads();

    {
        const int row = tid >> 2, cq = (tid & 3) * 4;
        bf16x4 o;
        #pragma unroll
        for (int j = 0; j < 4; ++j) {
            const float s = red[0][row][cq+j] + red[1][row][cq+j]
                          + red[2][row][cq+j] + red[3][row][cq+j];
            o[j] = (bf16)s;
        }
        *(bf16x4*)(A + (size_t)(row0+row)*KA + EE + cq) = o;
    }
    #pragma unroll
    for (int p = 0; p < 3; ++p) {
        const int id = p*256 + tid;       // 0..767
        const int row = id / 12, c = id % 12;
        *(bf16x4*)(A + (size_t)(row0+row)*KA + 784 + c*4) = (bf16x4){};
    }
}

// ---------------------------------------------------------------------------
// gemm_aug: C[t][f] = sum_k A[t][k]*B[f][k] + bias[f]  over KA=832.
// (r6-proven version: padded LDS, explicit vector staging)
// MODE 0: route to qfb(x 0.125*log2e)/kfb/vld bf16 (nh,l,d).  MODE 1: fp32 out.
// ---------------------------------------------------------------------------
template<int MODE>
__global__ __launch_bounds__(256) void gemm_aug(
    const bf16* __restrict__ A,
    const bf16* __restrict__ B,
    const float* __restrict__ bias,
    bf16* __restrict__ qo, bf16* __restrict__ ko, bf16* __restrict__ vo,
    float* __restrict__ fo)
{
    __shared__ bf16 As[128][72];
    __shared__ bf16 Bs[128][72];
    const int t0 = blockIdx.x * 128;
    const int f0 = blockIdx.y * 128;
    const int tid = threadIdx.x;
    const int wave = tid >> 6, lane = tid & 63;
    const int quad = lane >> 4, l16 = lane & 15;
    const int m0 = (wave & 1) * 64;
    const int n0 = (wave >> 1) * 64;

    const int third = (MODE == 0) ? (f0 / EE) : 0;
    const bf16* Aeff = (MODE == 0) ? (A + (size_t)third*TT*KA) : A;

    floatx4 acc[4][4];
    #pragma unroll
    for (int rt = 0; rt < 4; ++rt)
        #pragma unroll
        for (int ct = 0; ct < 4; ++ct) acc[rt][ct] = (floatx4){0.f,0.f,0.f,0.f};

    for (int kb = 0; kb < KA/64; ++kb) {
        __syncthreads();
        #pragma unroll
        for (int c = 0; c < 4; ++c) {
            int id = c*256 + tid;            // 0..1023 = 128 rows x 8 groups
            int row = id >> 3, cg = id & 7;
            *(bf16x8*)(&As[row][cg*8]) =
                *(const bf16x8*)(Aeff + (size_t)(t0+row)*KA + kb*64 + cg*8);
            *(bf16x8*)(&Bs[row][cg*8]) =
                *(const bf16x8*)(B + (size_t)(f0+row)*KA + kb*64 + cg*8);
        }
        __syncthreads();
        #pragma unroll
        for (int kc = 0; kc < 2; ++kc) {
            bf16x8 a[4], bfr[4];
            #pragma unroll
            for (int rt = 0; rt < 4; ++rt)
                a[rt] = *(const bf16x8*)(&As[m0 + rt*16 + l16][kc*32 + quad*8]);
            #pragma unroll
            for (int ct = 0; ct < 4; ++ct)
                bfr[ct] = *(const bf16x8*)(&Bs[n0 + ct*16 + l16][kc*32 + quad*8]);
            #pragma unroll
            for (int rt = 0; rt < 4; ++rt)
                #pragma unroll
                for (int ct = 0; ct < 4; ++ct)
                    acc[rt][ct] = __builtin_amdgcn_mfma_f32_16x16x32_bf16(
                        a[rt], bfr[ct], acc[rt][ct], 0, 0, 0);
        }
    }

    #pragma unroll
    for (int rt = 0; rt < 4; ++rt) {
        #pragma unroll
        for (int r = 0; r < 4; ++r) {
            const int t = t0 + m0 + rt*16 + quad*4 + r;
            #pragma unroll
            for (int ct = 0; ct < 4; ++ct) {
                const int fl = n0 + ct*16 + l16;
                float c = acc[rt][ct][r] + bias[f0 + fl];
                if (MODE == 0) {
                    const int fe = (f0 % EE) + fl;
                    const int h = fe >> 6, d = fe & 63;
                    const int l = t >> 2, n = t & 3;
                    const size_t idx = (((size_t)(n*HH + h)*LL) + l)*HD + d;
                    if (third == 0)      qo[idx] = (bf16)(c * 0.180336877f);
                    else if (third == 1) ko[idx] = (bf16)c;
                    else                 vo[idx] = (bf16)c;
                } else {
                    fo[(size_t)t*EE + f0 + fl] = c;
                }
            }
        }
    }
}

// ---------------------------------------------------------------------------
// vtrans: vld (nh,l,d) bf16 -> vfb (nh,d,l) bf16
// ---------------------------------------------------------------------------
__global__ __launch_bounds__(256) void vtrans(
    const bf16* __restrict__ vin, bf16* __restrict__ vout)
{
    __shared__ bf16 T[64][64];
    const int nh = blockIdx.x >> 5;
    const int l0 = (blockIdx.x & 31) * 64;
    const int tid = threadIdx.x;
    const bf16* src = vin + ((size_t)nh*LL + l0)*HD;
    #pragma unroll
    for (int c = 0; c < 2; ++c) {
        int id = c*256 + tid;
        int row = id >> 3, dg = id & 7;
        int pg = dg ^ (row & 7);
        *(bf16x8*)(&T[row][pg*8]) = *(const bf16x8*)(src + row*HD + dg*8);
    }
    __syncthreads();
    bf16* dst = vout + (size_t)nh*HD*LL;
    const int wave = tid >> 6, lane = tid & 63;
    #pragma unroll
    for (int it = 0; it < 2; ++it) {
        const int d  = it*32 + wave*8 + (lane >> 3);
        const int cg = lane & 7;
        bf16x8 vv;
        #pragma unroll
        for (int j = 0; j < 8; ++j) {
            const int lrow = cg*8 + j;
            const int pg = (d >> 3) ^ (lrow & 7);
            vv[j] = T[lrow][pg*8 + (d & 7)];
        }
        *(bf16x8*)(dst + (size_t)d*LL + l0 + cg*8) = vv;
    }
}

// ---------------------------------------------------------------------------
// attn_mfma: block = 64 queries of one (n,h); 4 waves x 16 query rows.
// Fixed-max softmax; Q in registers.  Ks/Vt are unpadded 64x64 tiles with
// XOR-swizzled column groups (conflict-free 16B stores AND b128 reads);
// Ps padded [72].  LDS 25.6 KB -> 6 blocks/CU with the 1536-block grid.
// ---------------------------------------------------------------------------
__global__ __launch_bounds__(256) void attn_mfma(
    const bf16* __restrict__ qf, const bf16* __restrict__ kf,
    const bf16* __restrict__ vf, bf16* __restrict__ Oa)
{
    __shared__ bf16 Ks[64][64];   // [row][ (cg^(row&7))*8 + j ]
    __shared__ bf16 Vt[64][64];   // same swizzle
    __shared__ bf16 Ps[64][72];   // padded, wave-private rows

    const int bid = blockIdx.x;
    const int nh = bid % 48;                 // same head -> same XCD
    const int l0 = (bid / 48) * 64;
    const int tid  = threadIdx.x;
    const int wave = tid >> 6;
    const int lane = tid & 63;
    const int quad = lane >> 4;
    const int l16  = lane & 15;
    const int m0   = wave * 16;
    const int lsw  = l16 & 7;                // read-swizzle key (= row&7)

    const bf16* qb = qf + (size_t)nh * LL * HD;
    const bf16* kb = kf + (size_t)nh * LL * HD;
    const bf16* vb = vf + (size_t)nh * HD * LL;

    // Q fragments (loop-invariant)
    bf16x8 aq[2];
    #pragma unroll
    for (int kc = 0; kc < 2; ++kc)
        aq[kc] = *(const bf16x8*)(
            qb + (size_t)(l0 + m0 + l16)*HD + kc*32 + quad*8);

    floatx4 oacc[4];
    float lrow[4];
    #pragma unroll
    for (int ct = 0; ct < 4; ++ct) oacc[ct] = (floatx4){0.f,0.f,0.f,0.f};
    #pragma unroll
    for (int r = 0; r < 4; ++r) lrow[r] = 0.f;

    for (int s0 = 0; s0 < LL; s0 += 64) {
        __syncthreads();
        #pragma unroll
        for (int it = 0; it < 2; ++it) {
            const int lin = it*256 + tid;    // 0..511 = 64 rows x 8 groups
            const int row = lin >> 3;
            const int cg  = lin & 7;
            const int sg  = cg ^ (row & 7);  // swizzled LDS column group
            *(bf16x8*)(&Ks[row][sg*8]) =
                *(const bf16x8*)(kb + (size_t)(s0+row)*HD + cg*8);
            *(bf16x8*)(&Vt[row][sg*8]) =
                *(const bf16x8*)(vb + (size_t)row*LL + s0 + cg*8);
        }
        __syncthreads();

        // ---- S = Q K^T ----
        floatx4 sf[4];
        #pragma unroll
        for (int ct = 0; ct < 4; ++ct) sf[ct] = (floatx4){0.f,0.f,0.f,0.f};
        #pragma unroll
        for (int kc = 0; kc < 2; ++kc) {
            bf16x8 bk[4];
            #pragma unroll
            for (int ct = 0; ct < 4; ++ct)
                bk[ct] = *(const bf16x8*)(&Ks[ct*16 + l16][((kc*4+quad)^lsw)*8]);
            #pragma unroll
            for (int ct = 0; ct < 4; ++ct)
                sf[ct] = __builtin_amdgcn_mfma_f32_16x16x32_bf16(
                    aq[kc], bk[ct], sf[ct], 0, 0, 0);
        }

        // ---- P = 2^S, partial row-sums ----
        #pragma unroll
        for (int r = 0; r < 4; ++r) {
            const int prow = m0 + quad*4 + r;
            float ps = 0.f;
            #pragma unroll
            for (int ct = 0; ct < 4; ++ct) {
                const float p = __builtin_exp2f(sf[ct][r]);
                Ps[prow][ct*16 + l16] = (bf16)p;
                ps += p;
            }
            lrow[r] += ps;
        }

        // ---- O += P V (P rows wave-private) ----
        #pragma unroll
        for (int kc = 0; kc < 2; ++kc) {
            const bf16x8 ap = *(const bf16x8*)(&Ps[m0 + l16][kc*32 + quad*8]);
            bf16x8 bv[4];
            #pragma unroll
            for (int ct = 0; ct < 4; ++ct)
                bv[ct] = *(const bf16x8*)(&Vt[ct*16 + l16][((kc*4+quad)^lsw)*8]);
            #pragma unroll
            for (int ct = 0; ct < 4; ++ct)
                oacc[ct] = __builtin_amdgcn_mfma_f32_16x16x32_bf16(
                    ap, bv[ct], oacc[ct], 0, 0, 0);
        }
    }

    // deferred row-sum reduction over the 16 l16 lanes
    #pragma unroll
    for (int r = 0; r < 4; ++r) {
        float s = lrow[r];
        #pragma unroll
        for (int off = 1; off < 16; off <<= 1)
            s += __shfl_xor(s, off, 64);
        lrow[r] = s;
    }

    const int n = nh / HH, h = nh % HH;
    #pragma unroll
    for (int r = 0; r < 4; ++r) {
        const float inv = 1.f / lrow[r];
        const int lq = l0 + m0 + quad*4 + r;
        const size_t t = (size_t)lq*NN + n;
        #pragma unroll
        for (int ct = 0; ct < 4; ++ct)
            Oa[t*KA + h*64 + ct*16 + l16] = (bf16)(oacc[ct][r] * inv);
    }
}

// ---------------------------------------------------------------------------
extern "C" void kernel_launch(void* const* d_in, const int* in_sizes, int n_in,
                              void* d_out, int out_size, void* d_ws, size_t ws_size,
                              hipStream_t stream) {
    const float* q   = (const float*)d_in[0];
    const float* k   = (const float*)d_in[1];
    const float* v   = (const float*)d_in[2];
    const float* W   = (const float*)d_in[3];
    const float* b   = (const float*)d_in[4];
    const float* qd  = (const float*)d_in[5];
    const float* qu  = (const float*)d_in[6];
    const float* kd  = (const float*)d_in[7];
    const float* ku  = (const float*)d_in[8];
    const float* vd  = (const float*)d_in[9];
    const float* vu  = (const float*)d_in[10];
    const float* Wo  = (const float*)d_in[11];
    const float* bo  = (const float*)d_in[12];
    const float* odw = (const float*)d_in[13];
    const float* ou  = (const float*)d_in[14];
    float* out = (float*)d_out;

    char* wsb = (char*)d_ws;
    bf16* Xa  = (bf16*)wsb;
    bf16* vfb = (bf16*)wsb;                                   // alias (Xa dead)
    bf16* Oa  = (bf16*)(wsb + (size_t)TT*EE*2);               // alias (+12.58MB)
    bf16* Wa  = (bf16*)(wsb + (size_t)3*TT*KA*2);
    bf16* qfb = (bf16*)((char*)Wa + (size_t)3072*KA*2);
    bf16* kfb = qfb + (size_t)TT*EE;
    bf16* vld = kfb + (size_t)TT*EE;
    bf16* Dm  = vld + (size_t)TT*EE;       // [4][16][768] bf16, 96 KB

    cast_x<<<3072, 256, 0, stream>>>(q, k, v, Xa);
    prep_w<<<3136, 256, 0, stream>>>(W, qu, ku, vu, Wo, ou, qd, kd, vd, odw, Wa, Dm);
    lora_rank16<1><<<3*TT/64, 256, 0, stream>>>(Xa, Dm);
    gemm_aug<0><<<dim3(TT/128, F3/128), 256, 0, stream>>>(
        Xa, Wa, b, qfb, kfb, vld, nullptr);
    vtrans<<<48*32, 256, 0, stream>>>(vld, vfb);
    attn_mfma<<<48*32, 256, 0, stream>>>(qfb, kfb, vfb, Oa);
    lora_rank16<0><<<TT/64, 256, 0, stream>>>(Oa, Dm);
    gemm_aug<1><<<dim3(TT/128, EE/128), 256, 0, stream>>>(
        Oa, Wa + (size_t)F3*KA, bo, nullptr, nullptr, nullptr, out);
}